// Round 4
// baseline (36.265 us; speedup 1.0000x reference)
//
#include <hip/hip_runtime.h>
#include <hip/hip_cooperative_groups.h>

namespace cg = cooperative_groups;

constexpr int NTOK  = 9216;             // 96*96
constexpr int BLOCK = 256;
constexpr int G     = 128;              // interpolation intervals
constexpr int TABP  = G + 4;            // 132 table points/batch (grid m = -1 .. G+2)
constexpr int BPB   = NTOK / BLOCK;     // 36 blocks per batch
constexpr int NBLK  = 2 * BPB;          // 72 blocks total
constexpr float LOG2E  = 1.44269504088896340736f;
constexpr float SCALE  = 0.125f;        // 64^-0.5
constexpr float XBOUND = 6.0f;          // conservative |x| bound (N(0,1), max ~4.3)

// Fused: phase 1 builds R-table (one grid point per wave), grid.sync,
// phase 2 Catmull-Rom interpolates one row per thread.
__global__ __launch_bounds__(BLOCK) void fused_kernel(
    const float* __restrict__ x,
    const float* __restrict__ w_qkv,
    const float* __restrict__ w_out,
    const float* __restrict__ b_out,
    float* __restrict__ tab,
    float* __restrict__ out)
{
    __shared__ float sx[NTOK];          // 36 KB: this batch's x

    const int bid   = blockIdx.x;
    const int batch = bid / BPB;
    const int blk   = bid % BPB;
    const int tid   = threadIdx.x;
    const int lane  = tid & 63;
    const int wave  = tid >> 6;

    // ---- stage x into LDS (float4, coalesced) ----
    const float4* __restrict__ x4 = reinterpret_cast<const float4*>(x + batch * NTOK);
    float4* s4 = reinterpret_cast<float4*>(sx);
#pragma unroll
    for (int i = 0; i < NTOK / 4 / BLOCK; ++i)      // 9 iters
        s4[tid + i * BLOCK] = x4[tid + i * BLOCK];
    __syncthreads();

    // ---- range parameters (log2 units) ----
    const float acoef = SCALE * w_qkv[0] * w_qkv[1] * LOG2E;  // a_i = acoef*x_i
    float delta = (2.0f * XBOUND * fabsf(acoef)) / (float)G;
    if (delta < 1e-30f) delta = 1e-30f;             // degenerate-weight guard
    const float amin = -XBOUND * fabsf(acoef);
    const float wvo  = w_qkv[2] * w_out[0];
    const float bo   = b_out[0];

    // ---- phase-2 precompute (independent of table; hide before sync) ----
    const int   row = blk * BLOCK + tid;
    const float xi  = sx[row];
    const float t   = (acoef * xi - amin) / delta;  // in (0, G)
    int i0 = (int)floorf(t);
    i0 = i0 < 0 ? 0 : (i0 > G - 1 ? G - 1 : i0);
    const float f  = t - (float)i0;
    const float f2 = f * f, f3 = f2 * f;
    const float cw0 = 0.5f * (-f3 + 2.f * f2 - f);
    const float cw1 = 0.5f * (3.f * f3 - 5.f * f2 + 2.f);
    const float cw2 = 0.5f * (-3.f * f3 + 4.f * f2 + f);
    const float cw3 = 0.5f * (f3 - f2);
    const float* __restrict__ tb = tab + batch * TABP + i0;   // stencil m = i0-1 .. i0+2

    // ---- phase 1: one table point per wave ----
    const int pidx = blk * 4 + wave;                // 0..143; need 0..131
    if (pidx < TABP) {
        const float ag = amin + (float)(pidx - 1) * delta;
        float s0 = 0.f, s1 = 0.f, s2 = 0.f, s3 = 0.f;
        float t0 = 0.f, t1 = 0.f, t2 = 0.f, t3 = 0.f;
        const float4* __restrict__ sv = reinterpret_cast<const float4*>(sx);
#pragma unroll 4
        for (int j = lane; j < NTOK / 4; j += 64) { // 36 iters
            float4 v = sv[j];
            float e0 = __builtin_amdgcn_exp2f(ag * v.x);
            float e1 = __builtin_amdgcn_exp2f(ag * v.y);
            float e2 = __builtin_amdgcn_exp2f(ag * v.z);
            float e3 = __builtin_amdgcn_exp2f(ag * v.w);
            s0 += e0; s1 += e1; s2 += e2; s3 += e3;
            t0 = fmaf(e0, v.x, t0);
            t1 = fmaf(e1, v.y, t1);
            t2 = fmaf(e2, v.z, t2);
            t3 = fmaf(e3, v.w, t3);
        }
        float S = (s0 + s1) + (s2 + s3);
        float T = (t0 + t1) + (t2 + t3);
#pragma unroll
        for (int off = 32; off; off >>= 1) {
            S += __shfl_xor(S, off);
            T += __shfl_xor(T, off);
        }
        if (lane == 0) tab[batch * TABP + pidx] = T / S;
    }

    // ---- grid-wide sync (table visible to all XCDs) ----
    __threadfence();
    cg::this_grid().sync();

    // ---- phase 2: interpolate one row per thread ----
    const float p0 = tb[0], p1 = tb[1], p2 = tb[2], p3 = tb[3];
    const float r  = cw0 * p0 + cw1 * p1 + cw2 * p2 + cw3 * p3;
    out[batch * NTOK + row] = fmaf(r, wvo, bo);
}

extern "C" void kernel_launch(void* const* d_in, const int* in_sizes, int n_in,
                              void* d_out, int out_size, void* d_ws, size_t ws_size,
                              hipStream_t stream) {
    const float* x     = (const float*)d_in[0];   // [2,1,96,96] f32
    const float* w_qkv = (const float*)d_in[1];   // [3]
    const float* w_out = (const float*)d_in[2];   // [1]
    const float* b_out = (const float*)d_in[3];   // [1]
    float* out = (float*)d_out;                   // [2*9216] f32
    float* tab = (float*)d_ws;                    // 2*132 f32 ~ 1 KB

    void* args[] = { (void*)&x, (void*)&w_qkv, (void*)&w_out,
                     (void*)&b_out, (void*)&tab, (void*)&out };
    hipLaunchCooperativeKernel((const void*)fused_kernel,
                               dim3(NBLK), dim3(BLOCK), args, 0, stream);
}

// Round 5
// 20.210 us; speedup vs baseline: 1.7944x; 1.7944x over previous
//
#include <hip/hip_runtime.h>

typedef float f32x2 __attribute__((ext_vector_type(2)));

constexpr int NTOK  = 9216;             // 96*96
constexpr int BLOCK = 512;              // 8 waves
constexpr int NWAVE = 8;
constexpr int BPB   = 18;               // blocks per batch
constexpr int ROWS  = NTOK / BPB;       // 512 rows per block (== BLOCK)
constexpr int NBLK  = 2 * BPB;          // 36 blocks total
constexpr int G     = 36;               // interpolation intervals
constexpr int TABP  = G + 4;            // 40 points (m = -1 .. 38), 5 per wave
constexpr int PPW   = TABP / NWAVE;     // 5 points per wave, balanced
constexpr float LOG2E  = 1.44269504088896340736f;
constexpr float SCALE  = 0.125f;        // 64^-0.5
constexpr float XBOUND = 6.0f;          // conservative |x| bound (N(0,1), max ~4.3)

__device__ __forceinline__ f32x2 pk_mul(f32x2 a, f32x2 b) {
    f32x2 d;
    asm("v_pk_mul_f32 %0, %1, %2" : "=v"(d) : "v"(a), "v"(b));
    return d;
}
__device__ __forceinline__ f32x2 pk_add(f32x2 a, f32x2 b) {
    f32x2 d;
    asm("v_pk_add_f32 %0, %1, %2" : "=v"(d) : "v"(a), "v"(b));
    return d;
}
__device__ __forceinline__ f32x2 pk_fma(f32x2 a, f32x2 b, f32x2 c) {
    f32x2 d;
    asm("v_pk_fma_f32 %0, %1, %2, %3" : "=v"(d) : "v"(a), "v"(b), "v"(c));
    return d;
}

// One block = 512 rows of one batch. The block builds the FULL R-table
// redundantly (wave w computes points w*5 .. w*5+4 over all 9216 j), then
// each thread Catmull-Rom-interpolates its row. No inter-block dependency.
__global__ __launch_bounds__(BLOCK) void fused_kernel(
    const float* __restrict__ x,
    const float* __restrict__ w_qkv,
    const float* __restrict__ w_out,
    const float* __restrict__ b_out,
    float* __restrict__ out)
{
    __shared__ float sx[NTOK];          // 36 KB
    __shared__ float tabS[TABP];

    const int bid   = blockIdx.x;
    const int batch = bid / BPB;
    const int blk   = bid % BPB;
    const int tid   = threadIdx.x;
    const int lane  = tid & 63;
    const int wave  = tid >> 6;

    // ---- stage x into LDS (float4, coalesced) ----
    const float4* __restrict__ x4 = reinterpret_cast<const float4*>(x + batch * NTOK);
    float4* s4 = reinterpret_cast<float4*>(sx);
    for (int i = tid; i < NTOK / 4; i += BLOCK)     // 4-5 iters
        s4[i] = x4[i];
    __syncthreads();

    // ---- range parameters (log2 units) ----
    const float acoef = SCALE * w_qkv[0] * w_qkv[1] * LOG2E;  // a_i = acoef*x_i
    float delta = (2.0f * XBOUND * fabsf(acoef)) / (float)G;
    if (delta < 1e-30f) delta = 1e-30f;             // degenerate-weight guard
    const float amin = -XBOUND * fabsf(acoef);

    // ---- phase 1: this wave's 5 table points, one LDS sweep ----
    float ag[PPW];
    f32x2 dl[PPW], dh[PPW], nl[PPW], nh[PPW];
#pragma unroll
    for (int k = 0; k < PPW; ++k) {
        ag[k] = amin + (float)(wave * PPW + k - 1) * delta;
        dl[k] = (f32x2){0.f, 0.f}; dh[k] = (f32x2){0.f, 0.f};
        nl[k] = (f32x2){0.f, 0.f}; nh[k] = (f32x2){0.f, 0.f};
    }
    const float4* __restrict__ sv = reinterpret_cast<const float4*>(sx);
#pragma unroll 2
    for (int j = lane; j < NTOK / 4; j += 64) {     // 36 iters
        float4 v = sv[j];
        const f32x2 vl = {v.x, v.y}, vh = {v.z, v.w};
#pragma unroll
        for (int k = 0; k < PPW; ++k) {
            const f32x2 a2 = {ag[k], ag[k]};
            f32x2 gl = pk_mul(a2, vl);
            f32x2 gh = pk_mul(a2, vh);
            f32x2 el = {__builtin_amdgcn_exp2f(gl[0]), __builtin_amdgcn_exp2f(gl[1])};
            f32x2 eh = {__builtin_amdgcn_exp2f(gh[0]), __builtin_amdgcn_exp2f(gh[1])};
            dl[k] = pk_add(dl[k], el);
            dh[k] = pk_add(dh[k], eh);
            nl[k] = pk_fma(el, vl, nl[k]);
            nh[k] = pk_fma(eh, vh, nh[k]);
        }
    }
#pragma unroll
    for (int k = 0; k < PPW; ++k) {
        float den = (dl[k][0] + dl[k][1]) + (dh[k][0] + dh[k][1]);
        float num = (nl[k][0] + nl[k][1]) + (nh[k][0] + nh[k][1]);
#pragma unroll
        for (int off = 32; off; off >>= 1) {
            den += __shfl_xor(den, off);
            num += __shfl_xor(num, off);
        }
        if (lane == 0) tabS[wave * PPW + k] = num / den;
    }
    __syncthreads();

    // ---- phase 2: one row per thread, Catmull-Rom from LDS table ----
    const int   row = blk * ROWS + tid;
    const float xi  = sx[row];
    const float t   = (acoef * xi - amin) / delta;  // in (0, G)
    int i0 = (int)floorf(t);
    i0 = i0 < 0 ? 0 : (i0 > G - 1 ? G - 1 : i0);
    const float f  = t - (float)i0;
    const float p0 = tabS[i0], p1 = tabS[i0 + 1], p2 = tabS[i0 + 2], p3 = tabS[i0 + 3];
    const float r  = p1 + 0.5f * f * ((p2 - p0)
                   + f * ((2.f * p0 - 5.f * p1 + 4.f * p2 - p3)
                   + f * (3.f * (p1 - p2) + (p3 - p0))));

    out[batch * NTOK + row] = fmaf(r, w_qkv[2] * w_out[0], b_out[0]);
}

extern "C" void kernel_launch(void* const* d_in, const int* in_sizes, int n_in,
                              void* d_out, int out_size, void* d_ws, size_t ws_size,
                              hipStream_t stream) {
    const float* x     = (const float*)d_in[0];   // [2,1,96,96] f32
    const float* w_qkv = (const float*)d_in[1];   // [3]
    const float* w_out = (const float*)d_in[2];   // [1]
    const float* b_out = (const float*)d_in[3];   // [1]
    float* out = (float*)d_out;                   // [2*9216] f32

    fused_kernel<<<dim3(NBLK), dim3(BLOCK), 0, stream>>>(x, w_qkv, w_out, b_out, out);
}

// Round 6
// 11.451 us; speedup vs baseline: 3.1670x; 1.7649x over previous
//
#include <hip/hip_runtime.h>

typedef float f32x2 __attribute__((ext_vector_type(2)));

constexpr int NTOK  = 9216;             // 96*96
constexpr int BLOCK = 512;              // 8 waves
constexpr int NWAVE = 8;
constexpr int BPB   = 18;               // blocks per batch
constexpr int ROWS  = NTOK / BPB;       // 512 rows per block (== BLOCK)
constexpr int NBLK  = 2 * BPB;          // 36 blocks total
constexpr int G     = 5;                // interpolation intervals over [alo, ahi]
constexpr int TABP  = G + 3;            // 8 points: m = -1 .. 6, one per wave
constexpr float LOG2E = 1.44269504088896340736f;
constexpr float SCALE = 0.125f;         // 64^-0.5

__device__ __forceinline__ f32x2 pk_mul(f32x2 a, f32x2 b) {
    f32x2 d;
    asm("v_pk_mul_f32 %0, %1, %2" : "=v"(d) : "v"(a), "v"(b));
    return d;
}
__device__ __forceinline__ f32x2 pk_add(f32x2 a, f32x2 b) {
    f32x2 d;
    asm("v_pk_add_f32 %0, %1, %2" : "=v"(d) : "v"(a), "v"(b));
    return d;
}
__device__ __forceinline__ f32x2 pk_fma(f32x2 a, f32x2 b, f32x2 c) {
    f32x2 d;
    asm("v_pk_fma_f32 %0, %1, %2, %3" : "=v"(d) : "v"(a), "v"(b), "v"(c));
    return d;
}

// One block = 512 rows of one batch. Block builds an 8-point R-table over the
// data-tight tilt range (wave w owns grid point m = w-1, sweeping all 9216 j
// from LDS), then each thread Catmull-Rom-interpolates its row. One graph node.
__global__ __launch_bounds__(BLOCK) void fused_kernel(
    const float* __restrict__ x,
    const float* __restrict__ w_qkv,
    const float* __restrict__ w_out,
    const float* __restrict__ b_out,
    float* __restrict__ out)
{
    __shared__ float sx[NTOK];          // 36 KB
    __shared__ float sred[2 * NWAVE];
    __shared__ float tabS[TABP];

    const int bid   = blockIdx.x;
    const int batch = bid / BPB;
    const int blk   = bid % BPB;
    const int tid   = threadIdx.x;
    const int lane  = tid & 63;
    const int wave  = tid >> 6;

    // ---- stage x into LDS (float4, coalesced) + per-batch min/max ----
    float vmax = -3.0e38f, vmin = 3.0e38f;
    const float4* __restrict__ x4 = reinterpret_cast<const float4*>(x + batch * NTOK);
    float4* s4 = reinterpret_cast<float4*>(sx);
    for (int i = tid; i < NTOK / 4; i += BLOCK) {   // 4-5 iters
        float4 v = x4[i];
        s4[i] = v;
        vmax = fmaxf(vmax, fmaxf(fmaxf(v.x, v.y), fmaxf(v.z, v.w)));
        vmin = fminf(vmin, fminf(fminf(v.x, v.y), fminf(v.z, v.w)));
    }
#pragma unroll
    for (int off = 32; off; off >>= 1) {
        vmax = fmaxf(vmax, __shfl_xor(vmax, off));
        vmin = fminf(vmin, __shfl_xor(vmin, off));
    }
    if (lane == 0) { sred[wave] = vmax; sred[NWAVE + wave] = vmin; }
    __syncthreads();
    float xmax = sred[0], xmin = sred[NWAVE];
#pragma unroll
    for (int w = 1; w < NWAVE; ++w) {
        xmax = fmaxf(xmax, sred[w]);
        xmin = fminf(xmin, sred[NWAVE + w]);
    }

    // ---- tilt range (log2 units), tight to the data ----
    const float acoef = SCALE * w_qkv[0] * w_qkv[1] * LOG2E;  // a_i = acoef*x_i
    const float alo = fminf(acoef * xmin, acoef * xmax);
    const float ahi = fmaxf(acoef * xmin, acoef * xmax);
    float delta = (ahi - alo) / (float)G;
    if (!(delta > 0.f)) delta = 1.0f;               // degenerate guard

    // ---- phase 1: wave w -> table point m = w-1, one full-j LDS sweep ----
    const float ag = alo + (float)(wave - 1) * delta;
    const f32x2 a2 = {ag, ag};
    f32x2 dl = {0.f, 0.f}, dh = {0.f, 0.f}, nl = {0.f, 0.f}, nh = {0.f, 0.f};
    const float4* __restrict__ sv = reinterpret_cast<const float4*>(sx);
#pragma unroll 4
    for (int j = lane; j < NTOK / 4; j += 64) {     // 36 iters
        float4 v = sv[j];
        const f32x2 vl = {v.x, v.y}, vh = {v.z, v.w};
        f32x2 gl = pk_mul(a2, vl);
        f32x2 gh = pk_mul(a2, vh);
        f32x2 el = {__builtin_amdgcn_exp2f(gl[0]), __builtin_amdgcn_exp2f(gl[1])};
        f32x2 eh = {__builtin_amdgcn_exp2f(gh[0]), __builtin_amdgcn_exp2f(gh[1])};
        dl = pk_add(dl, el);
        dh = pk_add(dh, eh);
        nl = pk_fma(el, vl, nl);
        nh = pk_fma(eh, vh, nh);
    }
    float S = (dl[0] + dl[1]) + (dh[0] + dh[1]);
    float T = (nl[0] + nl[1]) + (nh[0] + nh[1]);
#pragma unroll
    for (int off = 32; off; off >>= 1) {
        S += __shfl_xor(S, off);
        T += __shfl_xor(T, off);
    }
    if (lane == 0) tabS[wave] = T / S;              // slot w = point m = w-1
    __syncthreads();

    // ---- phase 2: one row per thread, Catmull-Rom from LDS table ----
    const int   row = blk * ROWS + tid;
    const float xi  = sx[row];
    const float t   = (acoef * xi - alo) / delta;   // in [0, G]
    int i0 = (int)floorf(t);
    i0 = i0 < 0 ? 0 : (i0 > G - 1 ? G - 1 : i0);
    const float f  = t - (float)i0;
    const float p0 = tabS[i0], p1 = tabS[i0 + 1], p2 = tabS[i0 + 2], p3 = tabS[i0 + 3];
    const float r  = p1 + 0.5f * f * ((p2 - p0)
                   + f * ((2.f * p0 - 5.f * p1 + 4.f * p2 - p3)
                   + f * (3.f * (p1 - p2) + (p3 - p0))));

    out[batch * NTOK + row] = fmaf(r, w_qkv[2] * w_out[0], b_out[0]);
}

extern "C" void kernel_launch(void* const* d_in, const int* in_sizes, int n_in,
                              void* d_out, int out_size, void* d_ws, size_t ws_size,
                              hipStream_t stream) {
    const float* x     = (const float*)d_in[0];   // [2,1,96,96] f32
    const float* w_qkv = (const float*)d_in[1];   // [3]
    const float* w_out = (const float*)d_in[2];   // [1]
    const float* b_out = (const float*)d_in[3];   // [1]
    float* out = (float*)d_out;                   // [2*9216] f32

    fused_kernel<<<dim3(NBLK), dim3(BLOCK), 0, stream>>>(x, w_qkv, w_out, b_out, out);
}

// Round 7
// 10.511 us; speedup vs baseline: 3.4502x; 1.0894x over previous
//
#include <hip/hip_runtime.h>

typedef float f32x2 __attribute__((ext_vector_type(2)));

constexpr int NTOK  = 9216;             // 96*96
constexpr int BLOCK = 512;              // 8 waves
constexpr int NWAVE = 8;
constexpr int BPB   = 18;               // blocks per batch
constexpr int ROWS  = NTOK / BPB;       // 512 rows per block (== BLOCK)
constexpr int NBLK  = 2 * BPB;          // 36 blocks total
constexpr int G     = 5;                // interpolation intervals over [alo, ahi]
constexpr int TABP  = G + 3;            // 8 points: m = -1 .. 6
constexpr int FPW   = NTOK / 2 / NWAVE; // 576 f32x2 per wave slice
constexpr int IPL   = FPW / 64;         // 9 f32x2 per lane
constexpr float LOG2E = 1.44269504088896340736f;
constexpr float SCALE = 0.125f;         // 64^-0.5

__device__ __forceinline__ f32x2 pk_mul(f32x2 a, f32x2 b) {
    f32x2 d;
    asm("v_pk_mul_f32 %0, %1, %2" : "=v"(d) : "v"(a), "v"(b));
    return d;
}
__device__ __forceinline__ f32x2 pk_add(f32x2 a, f32x2 b) {
    f32x2 d;
    asm("v_pk_add_f32 %0, %1, %2" : "=v"(d) : "v"(a), "v"(b));
    return d;
}
__device__ __forceinline__ f32x2 pk_fma(f32x2 a, f32x2 b, f32x2 c) {
    f32x2 d;
    asm("v_pk_fma_f32 %0, %1, %2, %3" : "=v"(d) : "v"(a), "v"(b), "v"(c));
    return d;
}

// One block = 512 rows of one batch. Each wave loads a 1/8 j-slice into
// registers, computes partial (den,num) for ALL 8 table points via a
// geometric exp-chain (2 exps + 7 muls per element), waves combine in LDS,
// then each thread Catmull-Rom-interpolates its row. One graph node.
__global__ __launch_bounds__(BLOCK) void fused_kernel(
    const float* __restrict__ x,
    const float* __restrict__ w_qkv,
    const float* __restrict__ w_out,
    const float* __restrict__ b_out,
    float* __restrict__ out)
{
    __shared__ float sred[2 * NWAVE];
    __shared__ float spart[NWAVE][2 * TABP];
    __shared__ float tabS[TABP];

    const int bid   = blockIdx.x;
    const int batch = bid / BPB;
    const int blk   = bid % BPB;
    const int tid   = threadIdx.x;
    const int lane  = tid & 63;
    const int wave  = tid >> 6;

    // ---- load this wave's slice into registers + slice min/max ----
    const f32x2* __restrict__ x2 = reinterpret_cast<const f32x2*>(x + batch * NTOK);
    f32x2 v[IPL];
    float vmax = -3.0e38f, vmin = 3.0e38f;
#pragma unroll
    for (int i = 0; i < IPL; ++i) {
        v[i] = x2[wave * FPW + i * 64 + lane];
        vmax = fmaxf(vmax, fmaxf(v[i][0], v[i][1]));
        vmin = fminf(vmin, fminf(v[i][0], v[i][1]));
    }
#pragma unroll
    for (int off = 32; off; off >>= 1) {
        vmax = fmaxf(vmax, __shfl_xor(vmax, off));
        vmin = fminf(vmin, __shfl_xor(vmin, off));
    }
    if (lane == 0) { sred[wave] = vmax; sred[NWAVE + wave] = vmin; }
    __syncthreads();
    float xmax = sred[0], xmin = sred[NWAVE];
#pragma unroll
    for (int w = 1; w < NWAVE; ++w) {
        xmax = fmaxf(xmax, sred[w]);
        xmin = fminf(xmin, sred[NWAVE + w]);
    }

    // ---- tilt range (log2 units), tight to the data ----
    const float acoef = SCALE * w_qkv[0] * w_qkv[1] * LOG2E;  // a_i = acoef*x_i
    const float alo = fminf(acoef * xmin, acoef * xmax);
    const float ahi = fmaxf(acoef * xmin, acoef * xmax);
    float delta = (ahi - alo) / (float)G;
    if (!(delta > 0.f)) delta = 1.0f;               // degenerate guard
    const float astart = alo - delta;               // table point m = -1

    // ---- phase 1: all 8 points over this wave's slice, exp-chain ----
    f32x2 den[TABP], num[TABP];
#pragma unroll
    for (int m = 0; m < TABP; ++m) {
        den[m] = (f32x2){0.f, 0.f};
        num[m] = (f32x2){0.f, 0.f};
    }
    const f32x2 as2 = {astart, astart}, dd2 = {delta, delta};
#pragma unroll
    for (int i = 0; i < IPL; ++i) {
        const f32x2 vv = v[i];
        f32x2 gu = pk_mul(as2, vv);
        f32x2 gw = pk_mul(dd2, vv);
        f32x2 u   = {__builtin_amdgcn_exp2f(gu[0]), __builtin_amdgcn_exp2f(gu[1])};
        f32x2 wst = {__builtin_amdgcn_exp2f(gw[0]), __builtin_amdgcn_exp2f(gw[1])};
#pragma unroll
        for (int m = 0; m < TABP; ++m) {
            den[m] = pk_add(den[m], u);
            num[m] = pk_fma(u, vv, num[m]);
            if (m < TABP - 1) u = pk_mul(u, wst);
        }
    }

    // ---- intra-wave reduction: pack {den,num} per point, butterfly ----
    f32x2 dn[TABP];
#pragma unroll
    for (int m = 0; m < TABP; ++m)
        dn[m] = (f32x2){den[m][0] + den[m][1], num[m][0] + num[m][1]};
#pragma unroll
    for (int off = 32; off; off >>= 1) {
#pragma unroll
        for (int m = 0; m < TABP; ++m) {
            f32x2 o;
            o[0] = __shfl_xor(dn[m][0], off);
            o[1] = __shfl_xor(dn[m][1], off);
            dn[m] = pk_add(dn[m], o);
        }
    }
    if (lane == 0) {
#pragma unroll
        for (int m = 0; m < TABP; ++m) {
            spart[wave][m]        = dn[m][0];
            spart[wave][TABP + m] = dn[m][1];
        }
    }
    __syncthreads();
    if (tid < TABP) {
        float S = 0.f, T = 0.f;
#pragma unroll
        for (int w = 0; w < NWAVE; ++w) {
            S += spart[w][tid];
            T += spart[w][TABP + tid];
        }
        tabS[tid] = T / S;
    }
    __syncthreads();

    // ---- phase 2: one row per thread, Catmull-Rom from LDS table ----
    const int   row = blk * ROWS + tid;
    const float xi  = x[batch * NTOK + row];
    const float t   = (acoef * xi - alo) / delta;   // in [0, G]
    int i0 = (int)floorf(t);
    i0 = i0 < 0 ? 0 : (i0 > G - 1 ? G - 1 : i0);
    const float f  = t - (float)i0;
    const float p0 = tabS[i0], p1 = tabS[i0 + 1], p2 = tabS[i0 + 2], p3 = tabS[i0 + 3];
    const float r  = p1 + 0.5f * f * ((p2 - p0)
                   + f * ((2.f * p0 - 5.f * p1 + 4.f * p2 - p3)
                   + f * (3.f * (p1 - p2) + (p3 - p0))));

    out[batch * NTOK + row] = fmaf(r, w_qkv[2] * w_out[0], b_out[0]);
}

extern "C" void kernel_launch(void* const* d_in, const int* in_sizes, int n_in,
                              void* d_out, int out_size, void* d_ws, size_t ws_size,
                              hipStream_t stream) {
    const float* x     = (const float*)d_in[0];   // [2,1,96,96] f32
    const float* w_qkv = (const float*)d_in[1];   // [3]
    const float* w_out = (const float*)d_in[2];   // [1]
    const float* b_out = (const float*)d_in[3];   // [1]
    float* out = (float*)d_out;                   // [2*9216] f32

    fused_kernel<<<dim3(NBLK), dim3(BLOCK), 0, stream>>>(x, w_qkv, w_out, b_out, out);
}